// Round 9
// baseline (185.163 us; speedup 1.0000x reference)
//
#include <hip/hip_runtime.h>
#include <stdint.h>

// RBF layer: out[b,c] = exp(-gamma * sqrt(max(||x_b||^2 - 2 x_b.c_c + ||c_c||^2, 0)))
// B=16384, D=1024, C=2048 (fp32 in/out).
// R9: int8 MFMA GEMM (mfma_i32_32x32x32_i8, 2x bf16 rate, EXACT i32 accum).
// 256x256 tile, BK=64 -> ONE phase per K-tile (16 MFMA), 16 phases/block
// (vs 64 in r8 -> 4x less phase overhead). 2-buffer ring, counted vmcnt(4),
// stages issued AFTER the MFMA cluster (race-free, ~2 phases of flight).
// LDS layout = per-wave-contiguous 1KB fragment blocks (zero bank conflicts by
// construction), realized via per-lane pre-permuted global source + linear
// global_load_lds dest (G21). Per-row dynamic i8 scales; fp32 norms exact;
// fused sqrt/exp epilogue.

typedef __attribute__((ext_vector_type(4))) int i32x4;
typedef __attribute__((ext_vector_type(16))) int i32x16;

#define BM 256
#define BN 256
#define BK 64

// One block per row: fp32 -> i8 quant (per-row scale) + fp32 sumsq + scale out.
// Requires K == 1024, 256 threads (1 float4/thread).
__global__ __launch_bounds__(256) void prep_i8(
    const float* __restrict__ in, unsigned char* __restrict__ qb,
    float2* __restrict__ info, int K) {
  int row = blockIdx.x;
  int tid = threadIdx.x;
  float4 v = ((const float4*)(in + (size_t)row * K))[tid];
  float ss = v.x * v.x + v.y * v.y + v.z * v.z + v.w * v.w;
  float am = fmaxf(fmaxf(fabsf(v.x), fabsf(v.y)), fmaxf(fabsf(v.z), fabsf(v.w)));
  for (int off = 32; off > 0; off >>= 1) {
    ss += __shfl_down(ss, off, 64);
    am = fmaxf(am, __shfl_down(am, off, 64));
  }
  __shared__ float pss[4], pam[4], sbc;
  int lane = tid & 63, w = tid >> 6;
  if (lane == 0) { pss[w] = ss; pam[w] = am; }
  __syncthreads();
  if (tid == 0) {
    float tss = pss[0] + pss[1] + pss[2] + pss[3];
    float tam = fmaxf(fmaxf(pam[0], pam[1]), fmaxf(pam[2], pam[3]));
    float s = tam > 0.f ? 127.f / tam : 0.f;
    info[row] = make_float2(tss, tam * (1.f / 127.f));
    sbc = s;
  }
  __syncthreads();
  float s = sbc;
  int qx = __float2int_rn(v.x * s), qy = __float2int_rn(v.y * s);
  int qz = __float2int_rn(v.z * s), qw = __float2int_rn(v.w * s);
  unsigned u = (unsigned)(qx & 255) | ((unsigned)(qy & 255) << 8) |
               ((unsigned)(qz & 255) << 16) | ((unsigned)(qw & 255) << 24);
  ((unsigned*)qb)[(size_t)row * (K >> 2) + tid] = u;
}

#define GLDS(gptr, lptr)                                                      \
  __builtin_amdgcn_global_load_lds(                                           \
      (const __attribute__((address_space(1))) unsigned int*)(gptr),          \
      (__attribute__((address_space(3))) unsigned int*)(lptr), 16, 0, 0)

#define DSR(dst, addr, imm)                                                   \
  asm volatile("ds_read_b128 %0, %1 offset:%c2"                              \
               : "=v"(dst) : "v"(addr), "i"(imm))

#define BARRIER __builtin_amdgcn_s_barrier()
#define LGKM0                                                                 \
  do {                                                                        \
    asm volatile("s_waitcnt lgkmcnt(0)" ::: "memory");                        \
    __builtin_amdgcn_sched_barrier(0);                                        \
  } while (0)
#define VMW(n) asm volatile("s_waitcnt vmcnt(" #n ")" ::: "memory")

#define MFMAI(a, b, c) __builtin_amdgcn_mfma_i32_32x32x32_i8((a), (b), (c), 0, 0, 0)

// 256x256 i8 GEMM, 1 phase per BK=64 K-tile, 2-buffer counted-vmcnt ring +
// fused RBF epilogue. A: [M][K] i8 (x). Bm: [N][K] i8 (centers).
// LDS per buffer (32KB): A region 16KB then B region 16KB. Fragment-block
// layout: byte addr = ((g*2+kk)*64 + l5*32 + r5)*16 + j for logical element
// (row = g*32 + r5, k = (kk*2+l5)*16 + j). Each wave's ds_read_b128 covers a
// contiguous 1KB block -> zero bank conflicts.
__global__ __launch_bounds__(512, 1) void rbf_gemm_i8(
    const unsigned char* __restrict__ A, const unsigned char* __restrict__ Bm,
    const float2* __restrict__ xinfo, const float2* __restrict__ cinfo,
    const float* __restrict__ gamma, float* __restrict__ out,
    int M, int N, int K) {
  __shared__ __align__(16) unsigned char lds[2 * 32768];

  int nbn = N / BN;
  int nwg = (M / BM) * nbn;
  int bid = blockIdx.x;
  int wg = bid;
  if ((nwg & 7) == 0) {  // XCD-aware swizzle (bijective: nwg % 8 == 0)
    int cpx = nwg >> 3;
    wg = (bid & 7) * cpx + (bid >> 3);
  }
  int bm = wg / nbn, bn = wg % nbn;

  int tid = threadIdx.x;
  int lane = tid & 63, wv = tid >> 6;
  int wm = wv >> 2;   // 0..1 : wave row (128 A-rows)
  int wn = wv & 3;    // 0..3 : wave col (64 B-rows)
  int l31 = lane & 31, l5 = lane >> 5;

  // ---- staging source decode: piece p -> (row = (p>>7)*32 + (p&31),
  //      k16-slot = ((p>>6)&1)*2 + ((p>>5)&1)).  LDS dest = piece*16 linear.
  const size_t Kz = (size_t)K;
  const unsigned char* As0;
  const unsigned char* As1;
  const unsigned char* Bs0;
  const unsigned char* Bs1;
  {
    int p0 = tid, p1 = tid + 512;
    size_t ro0 = (size_t)((p0 >> 7) * 32 + (p0 & 31)) * Kz +
                 (size_t)((((p0 >> 6) & 1) * 2 + ((p0 >> 5) & 1)) * 16);
    size_t ro1 = (size_t)((p1 >> 7) * 32 + (p1 & 31)) * Kz +
                 (size_t)((((p1 >> 6) & 1) * 2 + ((p1 >> 5) & 1)) * 16);
    As0 = A + (size_t)bm * BM * Kz + ro0;
    As1 = A + (size_t)bm * BM * Kz + ro1;
    Bs0 = Bm + (size_t)bn * BN * Kz + ro0;
    Bs1 = Bm + (size_t)bn * BN * Kz + ro1;
  }

#define STG4(TAU, BUFP)                                                       \
  do {                                                                        \
    GLDS(As0 + (size_t)(TAU) * 64, (BUFP) + tid * 16);                        \
    GLDS(As1 + (size_t)(TAU) * 64, (BUFP) + 8192 + tid * 16);                 \
    GLDS(Bs0 + (size_t)(TAU) * 64, (BUFP) + 16384 + tid * 16);                \
    GLDS(Bs1 + (size_t)(TAU) * 64, (BUFP) + 24576 + tid * 16);                \
  } while (0)

  // ---- fragment read bases (contiguous 1KB per wave-read) ----
  unsigned ldsBase =
      (unsigned)(size_t)(const __attribute__((address_space(3))) void*)&lds[0];
  unsigned baseA = ldsBase + (unsigned)(wm * 8192 + lane * 16);
  unsigned baseB = ldsBase + (unsigned)(16384 + wn * 4096 + lane * 16);

  i32x16 acc[4][2];
#pragma unroll
  for (int mf = 0; mf < 4; ++mf)
#pragma unroll
    for (int nf = 0; nf < 2; ++nf) acc[mf][nf] = (i32x16){0};

  // One phase per K-tile: reads -> barrier -> lgkm0 -> 16 MFMA -> stage(t+2)
  // -> counted vmcnt -> barrier.
#define PHASE(POFF, BUFP, TAU, DOSTG)                                         \
  do {                                                                        \
    i32x4 af[4][2], bf[2][2];                                                 \
    _Pragma("unroll") for (int mf = 0; mf < 4; ++mf) {                        \
      DSR(af[mf][0], baseA, (POFF) + mf * 2048);                              \
      DSR(af[mf][1], baseA, (POFF) + mf * 2048 + 1024);                       \
    }                                                                         \
    _Pragma("unroll") for (int nf = 0; nf < 2; ++nf) {                        \
      DSR(bf[nf][0], baseB, (POFF) + nf * 2048);                              \
      DSR(bf[nf][1], baseB, (POFF) + nf * 2048 + 1024);                       \
    }                                                                         \
    BARRIER;                                                                  \
    LGKM0;                                                                    \
    __builtin_amdgcn_s_setprio(1);                                            \
    _Pragma("unroll") for (int mf = 0; mf < 4; ++mf)                          \
      _Pragma("unroll") for (int nf = 0; nf < 2; ++nf)                        \
        acc[mf][nf] = MFMAI(af[mf][0], bf[nf][0], acc[mf][nf]);               \
    _Pragma("unroll") for (int mf = 0; mf < 4; ++mf)                          \
      _Pragma("unroll") for (int nf = 0; nf < 2; ++nf)                        \
        acc[mf][nf] = MFMAI(af[mf][1], bf[nf][1], acc[mf][nf]);               \
    __builtin_amdgcn_s_setprio(0);                                            \
    if (DOSTG) STG4(TAU, BUFP);                                               \
  } while (0)

  int nt = K / BK;  // 16 (launcher guarantees even, >= 4)

  // ---- prologue: tile0 -> buf0, tile1 -> buf1 (4 loads each) ----
  STG4(0, lds);
  STG4(1, lds + 32768);
  VMW(4);  // tile 0 resident; tile 1 in flight
  BARRIER;

  for (int t = 0; t < nt; t += 2) {
    // even phase: reads buf0, stages tile t+2 -> buf0
    PHASE(0, lds, t + 2, (t + 2) < nt);
    if (t < nt - 2) { VMW(4); } else { VMW(0); }
    BARRIER;
    // odd phase: reads buf1, stages tile t+3 -> buf1
    PHASE(32768, lds + 32768, t + 3, (t + 3) < nt);
    if (t + 1 < nt - 2) {
      VMW(4);
      BARRIER;
    } else if (t + 1 == nt - 2) {
      VMW(0);
      BARRIER;
    }
    // t+1 == nt-1: last phase, no wait/barrier needed
  }

  // ---- epilogue: 32x32 C/D layout col=lane&31, row=(reg&3)+8*(reg>>2)+4*l5
  // dot = acc * xscale[row] * cscale[col]; sq = x2+c2-2*dot; out=exp(-g*sqrt).
  float g = gamma[0];
  int rb0 = bm * BM + wm * 128 + 4 * l5;
  int cb0 = bn * BN + wn * 64 + l31;
#pragma unroll
  for (int nf = 0; nf < 2; ++nf) {
    int col = cb0 + nf * 32;
    float2 ci = cinfo[col];
#pragma unroll
    for (int mf = 0; mf < 4; ++mf) {
#pragma unroll
      for (int reg = 0; reg < 16; ++reg) {
        int row = rb0 + mf * 32 + (reg & 3) + 8 * (reg >> 2);
        float2 xi = xinfo[row];
        float dot = (float)acc[mf][nf][reg] * xi.y * ci.y;
        float sq = fmaxf(xi.x + ci.x - 2.f * dot, 0.f);
        out[(size_t)row * N + col] = __expf(-g * __builtin_sqrtf(sq));
      }
    }
  }
}

// Correctness fallback if workspace/shape doesn't fit (slow, fp32 vector path).
__global__ __launch_bounds__(256) void rbf_naive(
    const float* __restrict__ x, const float* __restrict__ cent,
    const float* __restrict__ gamma, float* __restrict__ out, int D, int N) {
  int row = blockIdx.x;
  int col = blockIdx.y * blockDim.x + threadIdx.x;
  extern __shared__ float xs[];
  for (int i = threadIdx.x; i < D; i += blockDim.x)
    xs[i] = x[(size_t)row * D + i];
  __syncthreads();
  if (col >= N) return;
  const float* cp = cent + (size_t)col * D;
  float s = 0.f;
  for (int d = 0; d < D; ++d) {
    float df = xs[d] - cp[d];
    s += df * df;
  }
  out[(size_t)row * N + col] = __expf(-gamma[0] * __builtin_sqrtf(fmaxf(s, 0.f)));
}

extern "C" void kernel_launch(void* const* d_in, const int* in_sizes, int n_in,
                              void* d_out, int out_size, void* d_ws, size_t ws_size,
                              hipStream_t stream) {
  const float* x = (const float*)d_in[0];
  const float* cent = (const float*)d_in[1];
  const float* gamma = (const float*)d_in[2];
  float* out = (float*)d_out;

  const int D = 1024;
  int Brows = in_sizes[0] / D;
  int C = in_sizes[1] / D;

  size_t qa = (size_t)Brows * D;           // x int8
  size_t qc = (size_t)C * D;               // centers int8
  size_t need = qa + qc + (size_t)Brows * 8 + (size_t)C * 8;
  bool can = (ws_size >= need) && (D == 1024) && (Brows % BM == 0) &&
             (C % BN == 0);

  if (!can) {
    dim3 grid(Brows, (C + 255) / 256);
    hipLaunchKernelGGL(rbf_naive, grid, dim3(256), D * sizeof(float), stream,
                       x, cent, gamma, out, D, C);
    return;
  }

  unsigned char* xb = (unsigned char*)d_ws;
  unsigned char* cb = xb + qa;
  float2* xinfo = (float2*)(xb + qa + qc);
  float2* cinfo = xinfo + Brows;

  hipLaunchKernelGGL(prep_i8, dim3(Brows), dim3(256), 0, stream, x, xb, xinfo, D);
  hipLaunchKernelGGL(prep_i8, dim3(C), dim3(256), 0, stream, cent, cb, cinfo, D);

  int nwg = (Brows / BM) * (C / BN);
  hipLaunchKernelGGL(rbf_gemm_i8, dim3(nwg), dim3(512), 0, stream,
                     xb, cb, xinfo, cinfo, gamma, out, Brows, C, D);
}

// Round 10
// 91.269 us; speedup vs baseline: 2.0288x; 2.0288x over previous
//
#include <hip/hip_runtime.h>
#include <stdint.h>

// RBF layer: out[b,c] = exp(-gamma * sqrt(max(||x||^2 - 2 x.c + ||c||^2, 0)))
// B=16384, D=1024, C=2048 (fp32 in/out).
// R10: int8 MFMA (mfma_i32_16x16x64_i8, 2x bf16 rate, exact i32 accum) on the
// r8 skeleton. 256x256 tile, BK=64, 8 waves (2Mx4N), wave 128x64 out.
// 3-buffer LDS ring (32KB/buf), 2 phases per K-tile {reads(8/4) + 2 GLDS ->
// barrier -> lgkm0+sched_barrier -> setprio 16 MFMA -> barrier}, counted
// vmcnt(4) at tile end only. COALESCED staging (r9 fix): 4 thr x 16B per 64-B
// row, sigma-row-swap + slot-XOR bank swizzle via pre-permuted global source
// (G21 both-sides). Per-row i8 scales; fp32 norms exact; fused sqrt/exp.

typedef __attribute__((ext_vector_type(4))) int i32x4;

#define BM 256
#define BN 256
#define BK 64

// One block per row: fp32 -> i8 quant (per-row scale) + fp32 sumsq.
__global__ __launch_bounds__(256) void prep_i8(
    const float* __restrict__ in, unsigned char* __restrict__ qb,
    float2* __restrict__ info, int K) {
  int row = blockIdx.x;
  int tid = threadIdx.x;
  float4 v = ((const float4*)(in + (size_t)row * K))[tid];
  float ss = v.x * v.x + v.y * v.y + v.z * v.z + v.w * v.w;
  float am = fmaxf(fmaxf(fabsf(v.x), fabsf(v.y)), fmaxf(fabsf(v.z), fabsf(v.w)));
  for (int off = 32; off > 0; off >>= 1) {
    ss += __shfl_down(ss, off, 64);
    am = fmaxf(am, __shfl_down(am, off, 64));
  }
  __shared__ float pss[4], pam[4], sbc;
  int lane = tid & 63, w = tid >> 6;
  if (lane == 0) { pss[w] = ss; pam[w] = am; }
  __syncthreads();
  if (tid == 0) {
    float tss = pss[0] + pss[1] + pss[2] + pss[3];
    float tam = fmaxf(fmaxf(pam[0], pam[1]), fmaxf(pam[2], pam[3]));
    float s = tam > 0.f ? 127.f / tam : 0.f;
    info[row] = make_float2(tss, tam * (1.f / 127.f));
    sbc = s;
  }
  __syncthreads();
  float s = sbc;
  int qx = __float2int_rn(v.x * s), qy = __float2int_rn(v.y * s);
  int qz = __float2int_rn(v.z * s), qw = __float2int_rn(v.w * s);
  unsigned u = (unsigned)(qx & 255) | ((unsigned)(qy & 255) << 8) |
               ((unsigned)(qz & 255) << 16) | ((unsigned)(qw & 255) << 24);
  ((unsigned*)qb)[(size_t)row * (K >> 2) + tid] = u;
}

#define GLDS(gptr, lptr)                                                      \
  __builtin_amdgcn_global_load_lds(                                           \
      (const __attribute__((address_space(1))) unsigned int*)(gptr),          \
      (__attribute__((address_space(3))) unsigned int*)(lptr), 16, 0, 0)

#define DSR(dst, addr, imm)                                                   \
  asm volatile("ds_read_b128 %0, %1 offset:%c2"                              \
               : "=v"(dst) : "v"(addr), "i"(imm))

#define BARRIER __builtin_amdgcn_s_barrier()
#define LGKM0                                                                 \
  do {                                                                        \
    asm volatile("s_waitcnt lgkmcnt(0)" ::: "memory");                        \
    __builtin_amdgcn_sched_barrier(0);                                        \
  } while (0)
#define VMW(n) asm volatile("s_waitcnt vmcnt(" #n ")" ::: "memory")

#define MFMAI8(a, b, c) __builtin_amdgcn_mfma_i32_16x16x64_i8((a), (b), (c), 0, 0, 0)

// LDS storage rule (per 256x64B matrix region): logical (row r, 16B slot s) at
// physical byte sigma(r)*64 + (s ^ (r&3))*16, sigma(r) = r ^ ((r>>2)&1).
// Bank check: frag read lane(l15,l4) hits bank 16*((l15&1)^((l15>>2)&1)) +
// 4*(l4^(l15&3)) -> 8 distinct banks per 8 lanes, 2-way total = free (m136).
__global__ __launch_bounds__(512, 1) void rbf_gemm_i8(
    const unsigned char* __restrict__ A, const unsigned char* __restrict__ Bm,
    const float2* __restrict__ xinfo, const float2* __restrict__ cinfo,
    const float* __restrict__ gamma, float* __restrict__ out,
    int M, int N, int K) {
  // 3 bufs x 32KB: A-tile 16KB (256 rows x 64B) then B-tile 16KB.
  __shared__ __align__(16) unsigned char lds[3 * 32768];

  int nbn = N / BN;
  int nwg = (M / BM) * nbn;
  int bid = blockIdx.x;
  int wg = bid;
  if ((nwg & 7) == 0) {  // XCD-aware swizzle (bijective: nwg % 8 == 0)
    int cpx = nwg >> 3;
    wg = (bid & 7) * cpx + (bid >> 3);
  }
  int bm = wg / nbn, bn = wg % nbn;

  int tid = threadIdx.x;
  int lane = tid & 63, wv = tid >> 6;
  int wm = wv >> 2;   // 0..1 : wave row (128 A-rows)
  int wn = wv & 3;    // 0..3 : wave col (64 B-rows)
  int l15 = lane & 15, l4 = lane >> 4;

  const size_t Kz = (size_t)K;

  // ---- staging: thread writes phys (row=tid>>2, slot=tid&3); source is the
  //      inverse-permuted logical element (coalesced 64-B row segments).
  int pr = tid >> 2;
  int lr = pr ^ ((pr >> 2) & 1);            // logical row (sigma involution)
  int ls = (tid & 3) ^ (lr & 3);            // logical slot
  const unsigned char* AgT = A + (size_t)bm * BM * Kz + (size_t)lr * Kz + ls * 16;
  const unsigned char* BgT = Bm + (size_t)bn * BN * Kz + (size_t)lr * Kz + ls * 16;
  size_t rstep = (size_t)128 * Kz;          // h=1 covers rows 128..255

#define STG_A(TAU, BUFS)                                                      \
  do {                                                                        \
    GLDS(AgT + (size_t)(TAU) * 64, (BUFS) + tid * 16);                        \
    GLDS(AgT + rstep + (size_t)(TAU) * 64, (BUFS) + 8192 + tid * 16);         \
  } while (0)
#define STG_B(TAU, BUFS)                                                      \
  do {                                                                        \
    GLDS(BgT + (size_t)(TAU) * 64, (BUFS) + 16384 + tid * 16);                \
    GLDS(BgT + rstep + (size_t)(TAU) * 64, (BUFS) + 24576 + tid * 16);        \
  } while (0)

  // ---- fragment read bases (A row = wm*128 + m*16 + l15, k = l4*16+j) ----
  int sl15 = l15 ^ ((l15 >> 2) & 1);
  int fsl = l4 ^ (l15 & 3);
  unsigned ldsBase =
      (unsigned)(size_t)(const __attribute__((address_space(3))) void*)&lds[0];
  unsigned aBase = ldsBase + (unsigned)(wm * 8192 + sl15 * 64 + fsl * 16);
  unsigned bBase = ldsBase + (unsigned)(16384 + wn * 4096 + sl15 * 64 + fsl * 16);

  i32x4 acc[8][4];
#pragma unroll
  for (int m = 0; m < 8; ++m)
#pragma unroll
    for (int n = 0; n < 4; ++n) acc[m][n] = (i32x4){0, 0, 0, 0};

  int nt = K / BK;  // 16

  // ---- prologue: tiles 0,1 -> bufs 0,1 ----
  STG_A(0, lds); STG_B(0, lds);
  STG_A(1, lds + 32768); STG_B(1, lds + 32768);
  VMW(4);  // tile 0 resident
  BARRIER;

  int rb = 0;
  for (int t = 0; t < nt; ++t) {
    unsigned bufOff = (unsigned)rb * 32768u;
    int sbi = rb + 2; if (sbi >= 3) sbi -= 3;
    unsigned char* bufS = lds + sbi * 32768;
    bool doStage = (t + 2 < nt);

    unsigned aAd = aBase + bufOff;
    unsigned bAd = bBase + bufOff;

    // ===== P1: reads A m0-3 + B n0-3; stage A(t+2); MFMA m0-3 x n0-3 =====
    i32x4 a0, a1, a2, a3, b0, b1, b2, b3;
    DSR(a0, aAd, 0);    DSR(a1, aAd, 1024);
    DSR(a2, aAd, 2048); DSR(a3, aAd, 3072);
    DSR(b0, bAd, 0);    DSR(b1, bAd, 1024);
    DSR(b2, bAd, 2048); DSR(b3, bAd, 3072);
    if (doStage) STG_A(t + 2, bufS);
    BARRIER;
    LGKM0;
    __builtin_amdgcn_s_setprio(1);
    acc[0][0] = MFMAI8(a0, b0, acc[0][0]);
    acc[0][1] = MFMAI8(a0, b1, acc[0][1]);
    acc[0][2] = MFMAI8(a0, b2, acc[0][2]);
    acc[0][3] = MFMAI8(a0, b3, acc[0][3]);
    acc[1][0] = MFMAI8(a1, b0, acc[1][0]);
    acc[1][1] = MFMAI8(a1, b1, acc[1][1]);
    acc[1][2] = MFMAI8(a1, b2, acc[1][2]);
    acc[1][3] = MFMAI8(a1, b3, acc[1][3]);
    acc[2][0] = MFMAI8(a2, b0, acc[2][0]);
    acc[2][1] = MFMAI8(a2, b1, acc[2][1]);
    acc[2][2] = MFMAI8(a2, b2, acc[2][2]);
    acc[2][3] = MFMAI8(a2, b3, acc[2][3]);
    acc[3][0] = MFMAI8(a3, b0, acc[3][0]);
    acc[3][1] = MFMAI8(a3, b1, acc[3][1]);
    acc[3][2] = MFMAI8(a3, b2, acc[3][2]);
    acc[3][3] = MFMAI8(a3, b3, acc[3][3]);
    __builtin_amdgcn_s_setprio(0);
    BARRIER;

    // ===== P2: reads A m4-7; stage B(t+2); MFMA m4-7 x n0-3 =====
    i32x4 a4, a5, a6, a7;
    DSR(a4, aAd, 4096); DSR(a5, aAd, 5120);
    DSR(a6, aAd, 6144); DSR(a7, aAd, 7168);
    if (doStage) STG_B(t + 2, bufS);
    BARRIER;
    LGKM0;
    __builtin_amdgcn_s_setprio(1);
    acc[4][0] = MFMAI8(a4, b0, acc[4][0]);
    acc[4][1] = MFMAI8(a4, b1, acc[4][1]);
    acc[4][2] = MFMAI8(a4, b2, acc[4][2]);
    acc[4][3] = MFMAI8(a4, b3, acc[4][3]);
    acc[5][0] = MFMAI8(a5, b0, acc[5][0]);
    acc[5][1] = MFMAI8(a5, b1, acc[5][1]);
    acc[5][2] = MFMAI8(a5, b2, acc[5][2]);
    acc[5][3] = MFMAI8(a5, b3, acc[5][3]);
    acc[6][0] = MFMAI8(a6, b0, acc[6][0]);
    acc[6][1] = MFMAI8(a6, b1, acc[6][1]);
    acc[6][2] = MFMAI8(a6, b2, acc[6][2]);
    acc[6][3] = MFMAI8(a6, b3, acc[6][3]);
    acc[7][0] = MFMAI8(a7, b0, acc[7][0]);
    acc[7][1] = MFMAI8(a7, b1, acc[7][1]);
    acc[7][2] = MFMAI8(a7, b2, acc[7][2]);
    acc[7][3] = MFMAI8(a7, b3, acc[7][3]);
    __builtin_amdgcn_s_setprio(0);
    // Counted gate: outstanding = t+1's 4 (from t-1) + t+2's 4 (this tile);
    // vmcnt(4) => tile t+1 fully resident before its P1 reads.
    if (t < nt - 2) {
      VMW(4);
      BARRIER;
    } else if (t == nt - 2) {
      VMW(0);
      BARRIER;
    }
    // t == nt-1: fall through to epilogue (no LDS use there)

    rb++; if (rb == 3) rb = 0;
  }

  // ---- epilogue: 16x16 C/D layout col = lane&15, row = (lane>>4)*4 + reg ----
  float g = gamma[0];
  int rb0 = bm * BM + wm * 128 + l4 * 4;
  int cb0 = bn * BN + wn * 64 + l15;
#pragma unroll
  for (int m = 0; m < 8; ++m) {
#pragma unroll
    for (int j = 0; j < 4; ++j) {
      int row = rb0 + m * 16 + j;
      float2 xi = xinfo[row];
      size_t ob = (size_t)row * N;
#pragma unroll
      for (int n = 0; n < 4; ++n) {
        int col = cb0 + n * 16;
        float2 ci = cinfo[col];
        float dot = (float)acc[m][n][j] * xi.y * ci.y;
        float sq = fmaxf(xi.x + ci.x - 2.f * dot, 0.f);
        out[ob + col] = __expf(-g * __builtin_sqrtf(sq));
      }
    }
  }
}

// Correctness fallback if workspace/shape doesn't fit (slow, fp32 vector path).
__global__ __launch_bounds__(256) void rbf_naive(
    const float* __restrict__ x, const float* __restrict__ cent,
    const float* __restrict__ gamma, float* __restrict__ out, int D, int N) {
  int row = blockIdx.x;
  int col = blockIdx.y * blockDim.x + threadIdx.x;
  extern __shared__ float xs[];
  for (int i = threadIdx.x; i < D; i += blockDim.x)
    xs[i] = x[(size_t)row * D + i];
  __syncthreads();
  if (col >= N) return;
  const float* cp = cent + (size_t)col * D;
  float s = 0.f;
  for (int d = 0; d < D; ++d) {
    float df = xs[d] - cp[d];
    s += df * df;
  }
  out[(size_t)row * N + col] = __expf(-gamma[0] * __builtin_sqrtf(fmaxf(s, 0.f)));
}

extern "C" void kernel_launch(void* const* d_in, const int* in_sizes, int n_in,
                              void* d_out, int out_size, void* d_ws, size_t ws_size,
                              hipStream_t stream) {
  const float* x = (const float*)d_in[0];
  const float* cent = (const float*)d_in[1];
  const float* gamma = (const float*)d_in[2];
  float* out = (float*)d_out;

  const int D = 1024;
  int Brows = in_sizes[0] / D;
  int C = in_sizes[1] / D;

  size_t qa = (size_t)Brows * D;
  size_t qc = (size_t)C * D;
  size_t need = qa + qc + (size_t)Brows * 8 + (size_t)C * 8;
  bool can = (ws_size >= need) && (D == 1024) && (Brows % BM == 0) &&
             (C % BN == 0);

  if (!can) {
    dim3 grid(Brows, (C + 255) / 256);
    hipLaunchKernelGGL(rbf_naive, grid, dim3(256), D * sizeof(float), stream,
                       x, cent, gamma, out, D, C);
    return;
  }

  unsigned char* xb = (unsigned char*)d_ws;
  unsigned char* cb = xb + qa;
  float2* xinfo = (float2*)(xb + qa + qc);
  float2* cinfo = xinfo + Brows;

  hipLaunchKernelGGL(prep_i8, dim3(Brows), dim3(256), 0, stream, x, xb, xinfo, D);
  hipLaunchKernelGGL(prep_i8, dim3(C), dim3(256), 0, stream, cent, cb, cinfo, D);

  int nwg = (Brows / BM) * (C / BN);
  hipLaunchKernelGGL(rbf_gemm_i8, dim3(nwg), dim3(512), 0, stream,
                     xb, cb, xinfo, cinfo, gamma, out, Brows, C, D);
}

// Round 11
// 89.668 us; speedup vs baseline: 2.0650x; 1.0179x over previous
//
#include <hip/hip_runtime.h>
#include <stdint.h>

// RBF layer: out[b,c] = exp(-gamma * sqrt(max(||x||^2 - 2 x.c + ||c||^2, 0)))
// B=16384, D=1024, C=2048 (fp32 in/out).
// R11: i8 MFMA (mfma_i32_16x16x64_i8) at the m97 OCCUPANCY point:
// 128x128 tile, 256 thr (4 waves 2x2, wave 64x64), BK=64, 3-buffer ring at
// 16KB/buf -> 48KB LDS -> 3 blocks/CU (12 waves/CU): barrier drains hide under
// foreign blocks (m114). ONE barrier per K-tile; counted vmcnt(4); stages
// issued early. Staging swizzle + fragment maps identical to r10 (verified).
// Per-row i8 scales; fp32 norms exact; fused sqrt/exp epilogue.

typedef __attribute__((ext_vector_type(4))) int i32x4;

#define BM 128
#define BN 128
#define BK 64

// One block per row: fp32 -> i8 quant (per-row scale) + fp32 sumsq.
__global__ __launch_bounds__(256) void prep_i8(
    const float* __restrict__ in, unsigned char* __restrict__ qb,
    float2* __restrict__ info, int K) {
  int row = blockIdx.x;
  int tid = threadIdx.x;
  float4 v = ((const float4*)(in + (size_t)row * K))[tid];
  float ss = v.x * v.x + v.y * v.y + v.z * v.z + v.w * v.w;
  float am = fmaxf(fmaxf(fabsf(v.x), fabsf(v.y)), fmaxf(fabsf(v.z), fabsf(v.w)));
  for (int off = 32; off > 0; off >>= 1) {
    ss += __shfl_down(ss, off, 64);
    am = fmaxf(am, __shfl_down(am, off, 64));
  }
  __shared__ float pss[4], pam[4], sbc;
  int lane = tid & 63, w = tid >> 6;
  if (lane == 0) { pss[w] = ss; pam[w] = am; }
  __syncthreads();
  if (tid == 0) {
    float tss = pss[0] + pss[1] + pss[2] + pss[3];
    float tam = fmaxf(fmaxf(pam[0], pam[1]), fmaxf(pam[2], pam[3]));
    float s = tam > 0.f ? 127.f / tam : 0.f;
    info[row] = make_float2(tss, tam * (1.f / 127.f));
    sbc = s;
  }
  __syncthreads();
  float s = sbc;
  int qx = __float2int_rn(v.x * s), qy = __float2int_rn(v.y * s);
  int qz = __float2int_rn(v.z * s), qw = __float2int_rn(v.w * s);
  unsigned u = (unsigned)(qx & 255) | ((unsigned)(qy & 255) << 8) |
               ((unsigned)(qz & 255) << 16) | ((unsigned)(qw & 255) << 24);
  ((unsigned*)qb)[(size_t)row * (K >> 2) + tid] = u;
}

#define GLDS(gptr, lptr)                                                      \
  __builtin_amdgcn_global_load_lds(                                           \
      (const __attribute__((address_space(1))) unsigned int*)(gptr),          \
      (__attribute__((address_space(3))) unsigned int*)(lptr), 16, 0, 0)

#define DSR(dst, addr, imm)                                                   \
  asm volatile("ds_read_b128 %0, %1 offset:%c2"                              \
               : "=v"(dst) : "v"(addr), "i"(imm))

#define BARRIER __builtin_amdgcn_s_barrier()
#define LGKM0                                                                 \
  do {                                                                        \
    asm volatile("s_waitcnt lgkmcnt(0)" ::: "memory");                        \
    __builtin_amdgcn_sched_barrier(0);                                        \
  } while (0)
#define VMW(n) asm volatile("s_waitcnt vmcnt(" #n ")" ::: "memory")

#define MFMAI8(a, b, c) __builtin_amdgcn_mfma_i32_16x16x64_i8((a), (b), (c), 0, 0, 0)

// LDS storage rule (per 128x64B region): logical (row r, 16B slot s) stored at
// physical byte sigma(r)*64 + (s ^ (r&3))*16, sigma(r) = r ^ ((r>>2)&1).
// Same involution as r10 (verified correct there).
__global__ __launch_bounds__(256) void rbf_gemm_i8(
    const unsigned char* __restrict__ A, const unsigned char* __restrict__ Bm,
    const float2* __restrict__ xinfo, const float2* __restrict__ cinfo,
    const float* __restrict__ gamma, float* __restrict__ out,
    int M, int N, int K) {
  // 3 bufs x 16KB: A-region 8KB (128 rows x 64B), B-region 8KB.
  __shared__ __align__(16) unsigned char lds[3 * 16384];

  int nbn = N / BN;
  int nwg = (M / BM) * nbn;
  int bid = blockIdx.x;
  int wg = bid;
  if ((nwg & 7) == 0) {  // XCD-aware swizzle (bijective: nwg % 8 == 0)
    int cpx = nwg >> 3;
    wg = (bid & 7) * cpx + (bid >> 3);
  }
  int bm = wg / nbn, bn = wg % nbn;

  int tid = threadIdx.x;
  int lane = tid & 63, wv = tid >> 6;
  int wm = wv >> 1;   // 0..1 : wave row (64 A-rows)
  int wn = wv & 1;    // 0..1 : wave col (64 B-rows)
  int l15 = lane & 15, l4 = lane >> 4;

  const size_t Kz = (size_t)K;

  // ---- staging: thread writes phys (row = h*64 + (tid>>2), slot = tid&3);
  //      source = inverse-permuted logical element (coalesced 64B segments).
  int pr = tid >> 2;                        // 0..63 within 64-row half
  int lr = pr ^ ((pr >> 2) & 1);            // sigma involution (bits <4 only)
  int ls = (tid & 3) ^ (lr & 3);            // logical slot
  const unsigned char* AgT = A + (size_t)bm * BM * Kz + (size_t)lr * Kz + ls * 16;
  const unsigned char* BgT = Bm + (size_t)bn * BN * Kz + (size_t)lr * Kz + ls * 16;
  size_t rstep = (size_t)64 * Kz;           // h=1 covers rows 64..127

#define STG4(TAU, BUFS)                                                       \
  do {                                                                        \
    GLDS(AgT + (size_t)(TAU) * 64, (BUFS) + tid * 16);                        \
    GLDS(AgT + rstep + (size_t)(TAU) * 64, (BUFS) + 4096 + tid * 16);         \
    GLDS(BgT + (size_t)(TAU) * 64, (BUFS) + 8192 + tid * 16);                 \
    GLDS(BgT + rstep + (size_t)(TAU) * 64, (BUFS) + 12288 + tid * 16);        \
  } while (0)

  // ---- fragment read bases (A row = wm*64 + m*16 + l15, k = l4*16 + j) ----
  int sl15 = l15 ^ ((l15 >> 2) & 1);
  int fsl = l4 ^ (l15 & 3);
  unsigned ldsBase =
      (unsigned)(size_t)(const __attribute__((address_space(3))) void*)&lds[0];
  unsigned aBase = ldsBase + (unsigned)(wm * 4096 + sl15 * 64 + fsl * 16);
  unsigned bBase = ldsBase + (unsigned)(8192 + wn * 4096 + sl15 * 64 + fsl * 16);

  i32x4 acc[4][4];
#pragma unroll
  for (int m = 0; m < 4; ++m)
#pragma unroll
    for (int n = 0; n < 4; ++n) acc[m][n] = (i32x4){0, 0, 0, 0};

  int nt = K / BK;  // 16

  // ---- prologue: tiles 0,1 -> bufs 0,1 ----
  STG4(0, lds);
  STG4(1, lds + 16384);
  VMW(4);  // tile 0 resident
  BARRIER;

  int rb = 0;
  for (int t = 0; t < nt; ++t) {
    unsigned bufOff = (unsigned)rb * 16384u;
    int sbi = rb + 2; if (sbi >= 3) sbi -= 3;
    unsigned char* bufS = lds + sbi * 16384;

    unsigned aAd = aBase + bufOff;
    unsigned bAd = bBase + bufOff;

    // ---- reads (own-data dep covered by LGKM0; buffer WAR by end barrier) --
    i32x4 a0, a1, a2, a3, b0, b1, b2, b3;
    DSR(a0, aAd, 0);    DSR(a1, aAd, 1024);
    DSR(a2, aAd, 2048); DSR(a3, aAd, 3072);
    DSR(b0, bAd, 0);    DSR(b1, bAd, 1024);
    DSR(b2, bAd, 2048); DSR(b3, bAd, 3072);
    // ---- stage t+2 early (long DMA flight; target buf last read in t-1,
    //      all its reads retired before t-1's end barrier) ----
    if (t + 2 < nt) STG4(t + 2, bufS);
    LGKM0;
    __builtin_amdgcn_s_setprio(1);
    acc[0][0] = MFMAI8(a0, b0, acc[0][0]);
    acc[0][1] = MFMAI8(a0, b1, acc[0][1]);
    acc[0][2] = MFMAI8(a0, b2, acc[0][2]);
    acc[0][3] = MFMAI8(a0, b3, acc[0][3]);
    acc[1][0] = MFMAI8(a1, b0, acc[1][0]);
    acc[1][1] = MFMAI8(a1, b1, acc[1][1]);
    acc[1][2] = MFMAI8(a1, b2, acc[1][2]);
    acc[1][3] = MFMAI8(a1, b3, acc[1][3]);
    acc[2][0] = MFMAI8(a2, b0, acc[2][0]);
    acc[2][1] = MFMAI8(a2, b1, acc[2][1]);
    acc[2][2] = MFMAI8(a2, b2, acc[2][2]);
    acc[2][3] = MFMAI8(a2, b3, acc[2][3]);
    acc[3][0] = MFMAI8(a3, b0, acc[3][0]);
    acc[3][1] = MFMAI8(a3, b1, acc[3][1]);
    acc[3][2] = MFMAI8(a3, b2, acc[3][2]);
    acc[3][3] = MFMAI8(a3, b3, acc[3][3]);
    __builtin_amdgcn_s_setprio(0);

    // Counted gate: outstanding = stage(t+1)(4, from t-1) + stage(t+2)(4, now);
    // vmcnt(4) => tile t+1 fully resident before any wave reads it.
    if (t < nt - 2) {
      VMW(4);
      BARRIER;
    } else if (t == nt - 2) {
      VMW(0);
      BARRIER;
    }
    // t == nt-1: epilogue next (no LDS use), no barrier needed.

    rb++; if (rb == 3) rb = 0;
  }

  // ---- epilogue: 16x16 C/D layout col = lane&15, row = (lane>>4)*4 + reg ----
  float g = gamma[0];
  int rb0 = bm * BM + wm * 64 + l4 * 4;
  int cb0 = bn * BN + wn * 64 + l15;
#pragma unroll
  for (int m = 0; m < 4; ++m) {
#pragma unroll
    for (int j = 0; j < 4; ++j) {
      int row = rb0 + m * 16 + j;
      float2 xi = xinfo[row];
      size_t ob = (size_t)row * N;
#pragma unroll
      for (int n = 0; n < 4; ++n) {
        int col = cb0 + n * 16;
        float2 ci = cinfo[col];
        float dot = (float)acc[m][n][j] * xi.y * ci.y;
        float sq = fmaxf(xi.x + ci.x - 2.f * dot, 0.f);
        out[ob + col] = __expf(-g * __builtin_sqrtf(sq));
      }
    }
  }
}

// Correctness fallback if workspace/shape doesn't fit (slow, fp32 vector path).
__global__ __launch_bounds__(256) void rbf_naive(
    const float* __restrict__ x, const float* __restrict__ cent,
    const float* __restrict__ gamma, float* __restrict__ out, int D, int N) {
  int row = blockIdx.x;
  int col = blockIdx.y * blockDim.x + threadIdx.x;
  extern __shared__ float xs[];
  for (int i = threadIdx.x; i < D; i += blockDim.x)
    xs[i] = x[(size_t)row * D + i];
  __syncthreads();
  if (col >= N) return;
  const float* cp = cent + (size_t)col * D;
  float s = 0.f;
  for (int d = 0; d < D; ++d) {
    float df = xs[d] - cp[d];
    s += df * df;
  }
  out[(size_t)row * N + col] = __expf(-gamma[0] * __builtin_sqrtf(fmaxf(s, 0.f)));
}

extern "C" void kernel_launch(void* const* d_in, const int* in_sizes, int n_in,
                              void* d_out, int out_size, void* d_ws, size_t ws_size,
                              hipStream_t stream) {
  const float* x = (const float*)d_in[0];
  const float* cent = (const float*)d_in[1];
  const float* gamma = (const float*)d_in[2];
  float* out = (float*)d_out;

  const int D = 1024;
  int Brows = in_sizes[0] / D;
  int C = in_sizes[1] / D;

  size_t qa = (size_t)Brows * D;
  size_t qc = (size_t)C * D;
  size_t need = qa + qc + (size_t)Brows * 8 + (size_t)C * 8;
  bool can = (ws_size >= need) && (D == 1024) && (Brows % BM == 0) &&
             (C % BN == 0);

  if (!can) {
    dim3 grid(Brows, (C + 255) / 256);
    hipLaunchKernelGGL(rbf_naive, grid, dim3(256), D * sizeof(float), stream,
                       x, cent, gamma, out, D, C);
    return;
  }

  unsigned char* xb = (unsigned char*)d_ws;
  unsigned char* cb = xb + qa;
  float2* xinfo = (float2*)(xb + qa + qc);
  float2* cinfo = xinfo + Brows;

  hipLaunchKernelGGL(prep_i8, dim3(Brows), dim3(256), 0, stream, x, xb, xinfo, D);
  hipLaunchKernelGGL(prep_i8, dim3(C), dim3(256), 0, stream, cent, cb, cinfo, D);

  int nwg = (Brows / BM) * (C / BN);
  hipLaunchKernelGGL(rbf_gemm_i8, dim3(nwg), dim3(256), 0, stream,
                     xb, cb, xinfo, cinfo, gamma, out, Brows, C, D);
}